// Round 1
// baseline (418.213 us; speedup 1.0000x reference)
//
#include <hip/hip_runtime.h>
#include <cstdint>
#include <cstddef>

#define BB 16
#define PP 19248
#define NOBJ 32
#define NCLS 81
#define POS_TH 0.5f
#define NEG_TH 0.4f
#define VAR0 0.1f
#define VAR1 0.2f
#define NEGPOS 3
#define MB 128   // priors per block in k_main

// ---------------- init ----------------
__global__ void k_init(unsigned long long* gkey, int* n_pos, float* acc) {
    int t = threadIdx.x + blockIdx.x * blockDim.x;
    if (t < BB * NOBJ) gkey[t] = 0ull;
    if (t < BB) n_pos[t] = 0;
    if (t == 0) { acc[0] = 0.0f; acc[1] = 0.0f; }
}

// ---------------- match: per-prior best gt + per-gt best prior ----------------
__global__ __launch_bounds__(256) void k_match(const float* __restrict__ priors,
                                               const float* __restrict__ gt_boxes,
                                               unsigned long long* __restrict__ gkey,
                                               float* __restrict__ bto,
                                               int* __restrict__ bti) {
    const int b = blockIdx.y;
    const int p = blockIdx.x * blockDim.x + threadIdx.x;
    __shared__ float sg[NOBJ * 4];
    for (int i = threadIdx.x; i < NOBJ * 4; i += blockDim.x)
        sg[i] = gt_boxes[b * NOBJ * 4 + i];
    __syncthreads();

    const bool valid = p < PP;
    float px1 = 0.f, py1 = 0.f, px2 = 0.f, py2 = 0.f, parea = 0.f;
    if (valid) {
        float4 pr = ((const float4*)priors)[p];
        float hw = pr.z / 2.0f, hh = pr.w / 2.0f;
        px1 = pr.x - hw; py1 = pr.y - hh; px2 = pr.x + hw; py2 = pr.y + hh;
        parea = (px2 - px1) * (py2 - py1);
    }

    float best_ov = -1.0f;
    int best_n = 0;
    const int lane = threadIdx.x & 63;

    for (int n = 0; n < NOBJ; ++n) {
        float gx1 = sg[n * 4 + 0], gy1 = sg[n * 4 + 1];
        float gx2 = sg[n * 4 + 2], gy2 = sg[n * 4 + 3];
        float iou = 0.0f;
        if (valid) {
#pragma clang fp contract(off)
            float ix1 = fmaxf(gx1, px1), iy1 = fmaxf(gy1, py1);
            float ix2 = fminf(gx2, px2), iy2 = fminf(gy2, py2);
            float iw = fmaxf(ix2 - ix1, 0.0f), ih = fmaxf(iy2 - iy1, 0.0f);
            float inter = iw * ih;
            float garea = (gx2 - gx1) * (gy2 - gy1);
            iou = inter / (garea + parea - inter);
        }
        if (iou > best_ov) { best_ov = iou; best_n = n; }

        unsigned long long key = 0ull;
        if (valid)
            key = (((unsigned long long)__float_as_uint(iou)) << 32) |
                  (unsigned long long)(0xFFFFFFFFu - (unsigned)p);
        for (int off = 32; off > 0; off >>= 1) {
            unsigned long long o = __shfl_down(key, off, 64);
            if (o > key) key = o;
        }
        if (lane == 0) atomicMax(&gkey[b * NOBJ + n], key);
    }

    if (valid) {
        bto[(size_t)b * PP + p] = best_ov;
        bti[(size_t)b * PP + p] = best_n;
    }
}

// ---------------- force: sequential last-wins scatter ----------------
__global__ void k_force(const unsigned long long* __restrict__ gkey,
                        float* __restrict__ bto, int* __restrict__ bti) {
    int b = threadIdx.x;
    if (b >= BB) return;
    for (int n = 0; n < NOBJ; ++n) {
        unsigned long long key = gkey[b * NOBJ + n];
        unsigned p = 0xFFFFFFFFu - (unsigned)(key & 0xFFFFFFFFull);
        bto[(size_t)b * PP + p] = 2.0f;
        bti[(size_t)b * PP + p] = n;
    }
}

__device__ __forceinline__ float sl1(float d) {
    float ad = fabsf(d);
    return ad < 1.0f ? 0.5f * d * d : ad - 0.5f;
}

// ---------------- main: classify, encode, smooth-L1, NLL, mine ----------------
__global__ __launch_bounds__(MB) void k_main(const float* __restrict__ loc_data,
                                             const float* __restrict__ conf_data,
                                             const float* __restrict__ priors,
                                             const float* __restrict__ gt_boxes,
                                             const int* __restrict__ gt_labels,
                                             const float* __restrict__ bto,
                                             const int* __restrict__ bti,
                                             float* __restrict__ mine,
                                             int* __restrict__ n_pos,
                                             float* __restrict__ acc) {
    const int b = blockIdx.y;
    const int p0 = blockIdx.x * MB;
    const int p = p0 + threadIdx.x;
    __shared__ __align__(16) float sconf[MB * NCLS];

    const int nvalid = min(MB, PP - p0);
    const float* src = conf_data + ((size_t)b * PP + p0) * NCLS;
    const int nv4 = (nvalid * NCLS) / 4;   // nvalid*81 is divisible by 4 here (128*81, 48*81)
    for (int i = threadIdx.x; i < nv4; i += MB)
        ((float4*)sconf)[i] = ((const float4*)src)[i];
    __syncthreads();

    float my_ll = 0.0f, my_lc = 0.0f;
    int my_pos = 0;
    const bool valid = p < PP;

    if (valid) {
        float ov = bto[(size_t)b * PP + p];
        int ti = bti[(size_t)b * PP + p];
        int conf = gt_labels[b * NOBJ + ti] + 1;
        if (ov < POS_TH) conf = -1;
        if (ov < NEG_TH) conf = 0;
        int ct = conf > 0 ? conf : 0;

        const float* row = sconf + threadIdx.x * NCLS;
        float m = row[0];
        for (int c = 1; c < NCLS; ++c) m = fmaxf(m, row[c]);
        float s = 0.0f;
        for (int c = 0; c < NCLS; ++c) s += expf(row[c] - m);
        float nll = m + logf(s) - row[ct];

        if (conf > 0) {
            my_pos = 1;
            my_lc = nll;
            float4 g = ((const float4*)gt_boxes)[b * NOBJ + ti];
            float4 pr = ((const float4*)priors)[p];
            float mcx = (g.x + g.z) / 2.0f, mcy = (g.y + g.w) / 2.0f;
            float mw = g.z - g.x, mh = g.w - g.y;
            float t0 = (mcx - pr.x) / (VAR0 * pr.z);
            float t1 = (mcy - pr.y) / (VAR0 * pr.w);
            float t2 = logf(mw / pr.z) / VAR1;
            float t3 = logf(mh / pr.w) / VAR1;
            float4 ld = ((const float4*)loc_data)[(size_t)b * PP + p];
            my_ll = sl1(ld.x - t0) + sl1(ld.y - t1) + sl1(ld.z - t2) + sl1(ld.w - t3);
        }
        mine[(size_t)b * PP + p] = (conf == 0) ? nll : 0.0f;
    }

    // block reduction (2 waves)
    for (int off = 32; off > 0; off >>= 1) {
        my_ll += __shfl_down(my_ll, off, 64);
        my_lc += __shfl_down(my_lc, off, 64);
        my_pos += __shfl_down(my_pos, off, 64);
    }
    __shared__ float r_ll[2], r_lc[2];
    __shared__ int r_pos[2];
    const int wid = threadIdx.x >> 6, lane = threadIdx.x & 63;
    if (lane == 0) { r_ll[wid] = my_ll; r_lc[wid] = my_lc; r_pos[wid] = my_pos; }
    __syncthreads();
    if (threadIdx.x == 0) {
        float ll = r_ll[0] + r_ll[1];
        float lc = r_lc[0] + r_lc[1];
        int np = r_pos[0] + r_pos[1];
        if (ll != 0.0f) atomicAdd(&acc[0], ll);
        if (lc != 0.0f) atomicAdd(&acc[1], lc);
        if (np) atomicAdd(&n_pos[b], np);
    }
}

// ---------------- select: per-batch radix top-k sum of mine ----------------
__global__ __launch_bounds__(256) void k_select(const float* __restrict__ mine,
                                                const int* __restrict__ n_pos,
                                                float* __restrict__ acc) {
    const int b = blockIdx.x;
    const float* mv = mine + (size_t)b * PP;
    const int k = min(NEGPOS * n_pos[b], PP - 1);

    __shared__ unsigned hist[256];
    __shared__ unsigned s_prefix;
    __shared__ int s_remaining;
    if (threadIdx.x == 0) { s_prefix = 0u; s_remaining = k; }
    __syncthreads();
    if (k <= 0) return;

    for (int pass = 0; pass < 4; ++pass) {
        const int shift = 24 - 8 * pass;
        const unsigned hm = (pass == 0) ? 0u : (0xFFFFFFFFu << (shift + 8));
        for (int i = threadIdx.x; i < 256; i += 256) hist[i] = 0u;
        __syncthreads();
        const unsigned pref = s_prefix;
        for (int i = threadIdx.x; i < PP; i += 256) {
            unsigned bits = __float_as_uint(mv[i]);
            if ((bits & hm) == pref) atomicAdd(&hist[(bits >> shift) & 0xFFu], 1u);
        }
        __syncthreads();
        if (threadIdx.x == 0) {
            int rem = s_remaining;
            unsigned cum = 0;
            int chosen = 0;
            for (int v = 255; v >= 0; --v) {
                unsigned c = hist[v];
                if (cum + c >= (unsigned)rem) { chosen = v; s_remaining = rem - (int)cum; break; }
                cum += c;
            }
            s_prefix = pref | ((unsigned)chosen << shift);
        }
        __syncthreads();
    }

    const unsigned T = s_prefix;
    float sum = 0.0f;
    unsigned cnt = 0;
    for (int i = threadIdx.x; i < PP; i += 256) {
        unsigned bits = __float_as_uint(mv[i]);
        if (bits > T) { sum += mv[i]; cnt++; }
    }
    for (int off = 32; off > 0; off >>= 1) {
        sum += __shfl_down(sum, off, 64);
        cnt += __shfl_down(cnt, off, 64);
    }
    __shared__ float rs[4];
    __shared__ unsigned rc[4];
    const int wid = threadIdx.x >> 6, lane = threadIdx.x & 63;
    if (lane == 0) { rs[wid] = sum; rc[wid] = cnt; }
    __syncthreads();
    if (threadIdx.x == 0) {
        float S = rs[0] + rs[1] + rs[2] + rs[3];
        int G = (int)(rc[0] + rc[1] + rc[2] + rc[3]);
        float neg = S + (float)(k - G) * __uint_as_float(T);
        atomicAdd(&acc[1], neg);
    }
}

// ---------------- final ----------------
__global__ void k_final(const float* __restrict__ acc,
                        const int* __restrict__ n_pos,
                        float* __restrict__ out) {
    if (threadIdx.x == 0 && blockIdx.x == 0) {
        int tp = 0;
        for (int b = 0; b < BB; ++b) tp += n_pos[b];
        float N = (float)max(tp, 1);
        out[0] = acc[0] / N;
        out[1] = acc[1] / N;
    }
}

extern "C" void kernel_launch(void* const* d_in, const int* in_sizes, int n_in,
                              void* d_out, int out_size, void* d_ws, size_t ws_size,
                              hipStream_t stream) {
    const float* loc    = (const float*)d_in[0];
    const float* conf   = (const float*)d_in[1];
    const float* priors = (const float*)d_in[2];
    const float* gt     = (const float*)d_in[3];
    const int*   labels = (const int*)d_in[4];
    float* out = (float*)d_out;

    char* ws = (char*)d_ws;
    const size_t SZ_BP = (size_t)BB * PP * 4;  // 1,231,872 B
    unsigned long long* gkey = (unsigned long long*)ws;            // 4096 B
    float* bto  = (float*)(ws + 4096);
    int*   bti  = (int*)  (ws + 4096 + SZ_BP);
    float* mine = (float*)(ws + 4096 + 2 * SZ_BP);
    int*   npos = (int*)  (ws + 4096 + 3 * SZ_BP);
    float* acc  = (float*)(ws + 4096 + 3 * SZ_BP + 256);

    k_init<<<1, 512, 0, stream>>>(gkey, npos, acc);

    dim3 mg((PP + 255) / 256, BB);
    k_match<<<mg, 256, 0, stream>>>(priors, gt, gkey, bto, bti);

    k_force<<<1, 64, 0, stream>>>(gkey, bto, bti);

    dim3 mg2((PP + MB - 1) / MB, BB);
    k_main<<<mg2, MB, 0, stream>>>(loc, conf, priors, gt, labels, bto, bti, mine, npos, acc);

    k_select<<<BB, 256, 0, stream>>>(mine, npos, acc);

    k_final<<<1, 64, 0, stream>>>(acc, npos, out);
}

// Round 2
// 375.635 us; speedup vs baseline: 1.1133x; 1.1133x over previous
//
#include <hip/hip_runtime.h>
#include <cstdint>
#include <cstddef>

#define BB 16
#define PP 19248
#define NOBJ 32
#define NCLS 81
#define POS_TH 0.5f
#define NEG_TH 0.4f
#define VAR0 0.1f
#define VAR1 0.2f
#define NEGPOS 3
#define MB 128   // priors per block in k_main

// ---------------- init ----------------
__global__ void k_init(unsigned long long* gkey, int* n_pos, float* acc) {
    int t = threadIdx.x + blockIdx.x * blockDim.x;
    if (t < BB * NOBJ) gkey[t] = 0ull;
    if (t < BB) n_pos[t] = 0;
    if (t == 0) { acc[0] = 0.0f; acc[1] = 0.0f; }
}

// ---------------- match: per-prior best gt + per-gt best prior ----------------
__global__ __launch_bounds__(256) void k_match(const float* __restrict__ priors,
                                               const float* __restrict__ gt_boxes,
                                               unsigned long long* __restrict__ gkey,
                                               float* __restrict__ bto,
                                               int* __restrict__ bti) {
    const int b = blockIdx.y;
    const int p = blockIdx.x * blockDim.x + threadIdx.x;
    __shared__ float sg[NOBJ * 4];
    for (int i = threadIdx.x; i < NOBJ * 4; i += blockDim.x)
        sg[i] = gt_boxes[b * NOBJ * 4 + i];
    __syncthreads();

    const bool valid = p < PP;
    float px1 = 0.f, py1 = 0.f, px2 = 0.f, py2 = 0.f, parea = 0.f;
    if (valid) {
        float4 pr = ((const float4*)priors)[p];
        float hw = pr.z / 2.0f, hh = pr.w / 2.0f;
        px1 = pr.x - hw; py1 = pr.y - hh; px2 = pr.x + hw; py2 = pr.y + hh;
        parea = (px2 - px1) * (py2 - py1);
    }

    float best_ov = -1.0f;
    int best_n = 0;
    const int lane = threadIdx.x & 63;

    for (int n = 0; n < NOBJ; ++n) {
        float gx1 = sg[n * 4 + 0], gy1 = sg[n * 4 + 1];
        float gx2 = sg[n * 4 + 2], gy2 = sg[n * 4 + 3];
        float iou = 0.0f;
        if (valid) {
#pragma clang fp contract(off)
            float ix1 = fmaxf(gx1, px1), iy1 = fmaxf(gy1, py1);
            float ix2 = fminf(gx2, px2), iy2 = fminf(gy2, py2);
            float iw = fmaxf(ix2 - ix1, 0.0f), ih = fmaxf(iy2 - iy1, 0.0f);
            float inter = iw * ih;
            float garea = (gx2 - gx1) * (gy2 - gy1);
            iou = inter / (garea + parea - inter);
        }
        if (iou > best_ov) { best_ov = iou; best_n = n; }

        unsigned long long key = 0ull;
        if (valid)
            key = (((unsigned long long)__float_as_uint(iou)) << 32) |
                  (unsigned long long)(0xFFFFFFFFu - (unsigned)p);
        for (int off = 32; off > 0; off >>= 1) {
            unsigned long long o = __shfl_down(key, off, 64);
            if (o > key) key = o;
        }
        if (lane == 0) atomicMax(&gkey[b * NOBJ + n], key);
    }

    if (valid) {
        bto[(size_t)b * PP + p] = best_ov;
        bti[(size_t)b * PP + p] = best_n;
    }
}

// ---------------- force: sequential last-wins scatter ----------------
__global__ void k_force(const unsigned long long* __restrict__ gkey,
                        float* __restrict__ bto, int* __restrict__ bti) {
    int b = threadIdx.x;
    if (b >= BB) return;
    for (int n = 0; n < NOBJ; ++n) {
        unsigned long long key = gkey[b * NOBJ + n];
        unsigned p = 0xFFFFFFFFu - (unsigned)(key & 0xFFFFFFFFull);
        bto[(size_t)b * PP + p] = 2.0f;
        bti[(size_t)b * PP + p] = n;
    }
}

__device__ __forceinline__ float sl1(float d) {
    float ad = fabsf(d);
    return ad < 1.0f ? 0.5f * d * d : ad - 0.5f;
}

// ---------------- main: classify, encode, smooth-L1, NLL, mine ----------------
__global__ __launch_bounds__(MB) void k_main(const float* __restrict__ loc_data,
                                             const float* __restrict__ conf_data,
                                             const float* __restrict__ priors,
                                             const float* __restrict__ gt_boxes,
                                             const int* __restrict__ gt_labels,
                                             const float* __restrict__ bto,
                                             const int* __restrict__ bti,
                                             float* __restrict__ mine,
                                             int* __restrict__ n_pos,
                                             float* __restrict__ acc) {
    const int b = blockIdx.y;
    const int p0 = blockIdx.x * MB;
    const int p = p0 + threadIdx.x;
    __shared__ __align__(16) float sconf[MB * NCLS];

    const int nvalid = min(MB, PP - p0);
    const float* src = conf_data + ((size_t)b * PP + p0) * NCLS;
    const int nv4 = (nvalid * NCLS) / 4;   // nvalid*81 is divisible by 4 here (128*81, 48*81)
    for (int i = threadIdx.x; i < nv4; i += MB)
        ((float4*)sconf)[i] = ((const float4*)src)[i];
    __syncthreads();

    float my_ll = 0.0f, my_lc = 0.0f;
    int my_pos = 0;
    const bool valid = p < PP;

    if (valid) {
        float ov = bto[(size_t)b * PP + p];
        int ti = bti[(size_t)b * PP + p];
        int conf = gt_labels[b * NOBJ + ti] + 1;
        if (ov < POS_TH) conf = -1;
        if (ov < NEG_TH) conf = 0;
        int ct = conf > 0 ? conf : 0;

        const float* row = sconf + threadIdx.x * NCLS;
        float m = row[0];
        for (int c = 1; c < NCLS; ++c) m = fmaxf(m, row[c]);
        float s = 0.0f;
        for (int c = 0; c < NCLS; ++c) s += expf(row[c] - m);
        float nll = m + logf(s) - row[ct];

        if (conf > 0) {
            my_pos = 1;
            my_lc = nll;
            float4 g = ((const float4*)gt_boxes)[b * NOBJ + ti];
            float4 pr = ((const float4*)priors)[p];
            float mcx = (g.x + g.z) / 2.0f, mcy = (g.y + g.w) / 2.0f;
            float mw = g.z - g.x, mh = g.w - g.y;
            float t0 = (mcx - pr.x) / (VAR0 * pr.z);
            float t1 = (mcy - pr.y) / (VAR0 * pr.w);
            float t2 = logf(mw / pr.z) / VAR1;
            float t3 = logf(mh / pr.w) / VAR1;
            float4 ld = ((const float4*)loc_data)[(size_t)b * PP + p];
            my_ll = sl1(ld.x - t0) + sl1(ld.y - t1) + sl1(ld.z - t2) + sl1(ld.w - t3);
        }
        mine[(size_t)b * PP + p] = (conf == 0) ? nll : 0.0f;
    }

    // block reduction (2 waves)
    for (int off = 32; off > 0; off >>= 1) {
        my_ll += __shfl_down(my_ll, off, 64);
        my_lc += __shfl_down(my_lc, off, 64);
        my_pos += __shfl_down(my_pos, off, 64);
    }
    __shared__ float r_ll[2], r_lc[2];
    __shared__ int r_pos[2];
    const int wid = threadIdx.x >> 6, lane = threadIdx.x & 63;
    if (lane == 0) { r_ll[wid] = my_ll; r_lc[wid] = my_lc; r_pos[wid] = my_pos; }
    __syncthreads();
    if (threadIdx.x == 0) {
        float ll = r_ll[0] + r_ll[1];
        float lc = r_lc[0] + r_lc[1];
        int np = r_pos[0] + r_pos[1];
        if (ll != 0.0f) atomicAdd(&acc[0], ll);
        if (lc != 0.0f) atomicAdd(&acc[1], lc);
        if (np) atomicAdd(&n_pos[b], np);
    }
}

// ---------------- select: per-batch radix top-k via ballot counting ----------------
// 8 passes x 4-bit digits. Wave-level counts use __ballot/popcount (no LDS
// atomics -> immune to value clustering that serialized the histogram version).
#define ST 1024
__global__ __launch_bounds__(ST) void k_select(const float* __restrict__ mine,
                                               const int* __restrict__ n_pos,
                                               float* __restrict__ acc) {
    const int b = blockIdx.x;
    const float* mv = mine + (size_t)b * PP;
    const int k = min(NEGPOS * n_pos[b], PP - 1);
    if (k <= 0) return;

    const int tid = threadIdx.x;
    const int wid = tid >> 6, lane = tid & 63;
    constexpr int NW = ST / 64;  // 16 waves

    __shared__ unsigned swh[NW * 16];   // per-wave 16-bin counts
    __shared__ unsigned stot[16];
    __shared__ unsigned s_prefix;
    __shared__ int s_rem;
    if (tid == 0) { s_prefix = 0u; s_rem = k; }
    __syncthreads();

    for (int pass = 0; pass < 8; ++pass) {
        const int shift = 28 - 4 * pass;
        const unsigned hm = (pass == 0) ? 0u : (0xFFFFFFFFu << (shift + 4));
        const unsigned prefix = s_prefix;

        unsigned cnt[16];
#pragma unroll
        for (int v = 0; v < 16; ++v) cnt[v] = 0u;

        for (int i = tid; i < PP; i += ST) {
            unsigned bits = __float_as_uint(mv[i]);
            // key = digit if prefix matches, else 16 (counts in no bin)
            unsigned key = ((bits & hm) == prefix) ? ((bits >> shift) & 15u) : 16u;
#pragma unroll
            for (int v = 0; v < 16; ++v)
                cnt[v] += (unsigned)__popcll(__ballot(key == (unsigned)v));
        }
        if (lane == 0) {
#pragma unroll
            for (int v = 0; v < 16; ++v) swh[wid * 16 + v] = cnt[v];
        }
        __syncthreads();
        if (tid < 16) {
            unsigned t = 0;
#pragma unroll
            for (int w = 0; w < NW; ++w) t += swh[w * 16 + tid];
            stot[tid] = t;
        }
        __syncthreads();
        if (tid == 0) {
            int rem = s_rem;
            unsigned cum = 0;
            int chosen = 0;
            for (int v = 15; v >= 0; --v) {
                unsigned c = stot[v];
                if (cum + c >= (unsigned)rem) { chosen = v; s_rem = rem - (int)cum; break; }
                cum += c;
            }
            s_prefix = prefix | ((unsigned)chosen << shift);
        }
        __syncthreads();
    }

    const unsigned T = s_prefix;  // exact bits of k-th largest value
    float sum = 0.0f;
    unsigned cnt = 0;
    for (int i = tid; i < PP; i += ST) {
        float v = mv[i];
        unsigned bits = __float_as_uint(v);
        if (bits > T) { sum += v; cnt++; }
    }
    for (int off = 32; off > 0; off >>= 1) {
        sum += __shfl_down(sum, off, 64);
        cnt += __shfl_down(cnt, off, 64);
    }
    __shared__ float rs[NW];
    __shared__ unsigned rc[NW];
    if (lane == 0) { rs[wid] = sum; rc[wid] = cnt; }
    __syncthreads();
    if (tid == 0) {
        float S = 0.0f;
        int G = 0;
        for (int w = 0; w < NW; ++w) { S += rs[w]; G += (int)rc[w]; }
        float neg = S + (float)(k - G) * __uint_as_float(T);
        atomicAdd(&acc[1], neg);
    }
}

// ---------------- final ----------------
__global__ void k_final(const float* __restrict__ acc,
                        const int* __restrict__ n_pos,
                        float* __restrict__ out) {
    if (threadIdx.x == 0 && blockIdx.x == 0) {
        int tp = 0;
        for (int b = 0; b < BB; ++b) tp += n_pos[b];
        float N = (float)max(tp, 1);
        out[0] = acc[0] / N;
        out[1] = acc[1] / N;
    }
}

extern "C" void kernel_launch(void* const* d_in, const int* in_sizes, int n_in,
                              void* d_out, int out_size, void* d_ws, size_t ws_size,
                              hipStream_t stream) {
    const float* loc    = (const float*)d_in[0];
    const float* conf   = (const float*)d_in[1];
    const float* priors = (const float*)d_in[2];
    const float* gt     = (const float*)d_in[3];
    const int*   labels = (const int*)d_in[4];
    float* out = (float*)d_out;

    char* ws = (char*)d_ws;
    const size_t SZ_BP = (size_t)BB * PP * 4;  // 1,231,872 B
    unsigned long long* gkey = (unsigned long long*)ws;            // 4096 B
    float* bto  = (float*)(ws + 4096);
    int*   bti  = (int*)  (ws + 4096 + SZ_BP);
    float* mine = (float*)(ws + 4096 + 2 * SZ_BP);
    int*   npos = (int*)  (ws + 4096 + 3 * SZ_BP);
    float* acc  = (float*)(ws + 4096 + 3 * SZ_BP + 256);

    k_init<<<1, 512, 0, stream>>>(gkey, npos, acc);

    dim3 mg((PP + 255) / 256, BB);
    k_match<<<mg, 256, 0, stream>>>(priors, gt, gkey, bto, bti);

    k_force<<<1, 64, 0, stream>>>(gkey, bto, bti);

    dim3 mg2((PP + MB - 1) / MB, BB);
    k_main<<<mg2, MB, 0, stream>>>(loc, conf, priors, gt, labels, bto, bti, mine, npos, acc);

    k_select<<<BB, ST, 0, stream>>>(mine, npos, acc);

    k_final<<<1, 64, 0, stream>>>(acc, npos, out);
}